// Round 2
// baseline (431.014 us; speedup 1.0000x reference)
//
#include <hip/hip_runtime.h>

// clip_nce: Q=16384 queries, V=4096 videos, scores [Q,V] fp32, labels [Q] int.
// R6 -> R7: REVERT R6's fusions (regressed +39us: in-loop labels s_load shares
// lgkmcnt with the shfl chain; ticket forced 192 threadfences). Back to the
// proven R5 structure, ONE change: strip the per-iteration 6-shfl + LDS-atomic
// reduction out of the streaming loop. Row partials accumulate in a fully
// unrolled register array rp[32]; the 32x(wave-reduce + atomic) runs ONCE after
// the stream. Theory: the ~7 dependent DS ops per iteration were the 2.4 TB/s
// cap, not the L1 path. init_pass -> hipMemsetAsync (2us, zero risk).

#define QN 16384
#define VN 4096
#define NB 2048
#define TB 256
#define STEP (NB * TB)                    // float4s per sweep step = 524288 (8 MB)
#define ITERS ((QN * (VN / 4)) / STEP)    // 32
#define ROWS_PER_STEP (STEP / (VN / 4))   // 512

typedef float f32x4 __attribute__((ext_vector_type(4)));

// workspace layout in floats (~8.4 MiB):
#define COLCOMP_OFF 0                     // NB*1024 compact column partials
#define ROWSUM_OFF  (NB * 1024)           // QN: sum exp per row (global atomics)
#define NOMSUM_OFF  (ROWSUM_OFF + QN)     // VN: sum exp(s) per label
#define COLSUM_OFF  (NOMSUM_OFF + VN)     // VN: column exp-sums (natural order)
#define ACC_OFF     (COLSUM_OFF + VN)     // [0]=sum log rowsum, [1]=sum s
#define ZERO_FLOATS (QN + VN + VN + 8)    // rowsum + nomsum + colsum + acc

// 16384 label gathers (one cache line each) + nomsum + sum(s)
__global__ __launch_bounds__(256) void gather_pass(const float* __restrict__ scores,
                                                   const int* __restrict__ labels,
                                                   float* __restrict__ ws) {
    float* nomsum = ws + NOMSUM_OFF;
    float* acc    = ws + ACC_OFF;
    const int i = blockIdx.x * 256 + threadIdx.x;
    const int lab = labels[i];
    const float s = scores[(size_t)i * VN + lab];
    unsafeAtomicAdd(&nomsum[lab], __expf(s));
    float v = s;
#pragma unroll
    for (int off = 32; off >= 1; off >>= 1)
        v += __shfl_down(v, off);
    if ((threadIdx.x & 63) == 0) unsafeAtomicAdd(&acc[1], v);
}

// Grid-stride dense sweep with NON-TEMPORAL reads.
// Thread (b,t): float4 index k*STEP + b*256 + t.
//  row = k*ROWS_PER_STEP + (b>>2)  (whole block in one row per iteration)
//  columns = (b&3)*1024 + t*4 + {0..3}  (fixed for all k -> register colacc)
// Streaming loop is PURE: load -> 4 exp -> 7 adds -> rp[k]. No DS ops, no
// atomics, no cross-lane until after the last load.
__global__ __launch_bounds__(256, 6) void main_pass(const float* __restrict__ scores,
                                                    float* __restrict__ ws) {
    float* rowsum  = ws + ROWSUM_OFF;
    float* colcomp = ws + COLCOMP_OFF;
    const int tid  = threadIdx.x;
    const int b    = blockIdx.x;
    const int lane = tid & 63;
    const f32x4* sp = reinterpret_cast<const f32x4*>(scores);
    const int base      = b * TB + tid;
    const int rowInStep = b >> 2;          // constant per block

    float c0 = 0.f, c1 = 0.f, c2 = 0.f, c3 = 0.f;
    float rp[ITERS];                       // per-thread row partials (registers)

#pragma unroll
    for (int k = 0; k < ITERS; ++k) {
        f32x4 x = __builtin_nontemporal_load(&sp[(size_t)k * STEP + base]);
        float e0 = __expf(x.x), e1 = __expf(x.y);
        float e2 = __expf(x.z), e3 = __expf(x.w);
        c0 += e0; c1 += e1; c2 += e2; c3 += e3;
        rp[k] = (e0 + e1) + (e2 + e3);
    }

    // compact col partials: colcomp[b*256*4 + t*4 + j] <-> col (b&3)*1024 + t*4 + j
    f32x4 o; o.x = c0; o.y = c1; o.z = c2; o.w = c3;
    reinterpret_cast<f32x4*>(colcomp)[b * TB + tid] = o;

    // deferred row reduction: 32 independent 6-shfl chains, pipelined, once.
    // 16 atomics per row address total across the grid (4 blocks x 4 waves).
#pragma unroll
    for (int k = 0; k < ITERS; ++k) {
        float v = rp[k];
#pragma unroll
        for (int off = 32; off >= 1; off >>= 1)
            v += __shfl_down(v, off);
        if (lane == 0)
            unsafeAtomicAdd(&rowsum[k * ROWS_PER_STEP + rowInStep], v);
    }
}

// blocks [0,128): colsum from compact partials (8 MiB read).
//   block = q*32 + cc*8 + mg: quarter q, col-chunk cc, m-range mg
// blocks [128,192): sum log rowsum -> acc[0]
__global__ __launch_bounds__(256) void reduce_pass(float* __restrict__ ws) {
    const float* colcomp = ws + COLCOMP_OFF;
    const float* rowsum  = ws + ROWSUM_OFF;
    float* colsum = ws + COLSUM_OFF;
    float* acc    = ws + ACC_OFF;
    const int tid = threadIdx.x;

    if (blockIdx.x < 128) {
        const int q  = blockIdx.x >> 5;          // column quarter 0..3
        const int cc = (blockIdx.x >> 3) & 3;    // 256-col chunk 0..3
        const int mg = blockIdx.x & 7;           // m-range 0..7
        const int c  = cc * 256 + tid;           // col within quarter [0,1024)
        float sum = 0.0f;
#pragma unroll 4
        for (int m = mg * 64; m < mg * 64 + 64; ++m)
            sum += colcomp[(size_t)(4 * m + q) * 1024 + c];
        unsafeAtomicAdd(&colsum[q * 1024 + c], sum);
    } else {
        const int idx = (blockIdx.x - 128) * 256 + tid;
        float v = __logf(rowsum[idx]);
#pragma unroll
        for (int off = 32; off >= 1; off >>= 1)
            v += __shfl_down(v, off);
        if ((tid & 63) == 0) unsafeAtomicAdd(&acc[0], v);
    }
}

__global__ __launch_bounds__(256) void final_pass(const float* __restrict__ ws,
                                                  float* __restrict__ out) {
    const float* nomsum = ws + NOMSUM_OFF;
    const float* colsum = ws + COLSUM_OFF;
    const float* acc    = ws + ACC_OFF;
    const int tid = threadIdx.x;

    float local = 0.0f;
    for (int c = tid; c < VN; c += 256)
        local += __logf(colsum[c]) - __logf(nomsum[c]);
#pragma unroll
    for (int off = 32; off >= 1; off >>= 1)
        local += __shfl_down(local, off);
    __shared__ float red[4];
    const int wid = tid >> 6, lane = tid & 63;
    if (lane == 0) red[wid] = local;
    __syncthreads();
    if (tid == 0) {
        const float v2t = (red[0] + red[1]) + (red[2] + red[3]);
        // mean(log rowsum - s) + mean(log colsum - log nomsum)
        out[0] = (acc[0] - acc[1]) * (1.0f / QN) + v2t * (1.0f / VN);
    }
}

extern "C" void kernel_launch(void* const* d_in, const int* in_sizes, int n_in,
                              void* d_out, int out_size, void* d_ws, size_t ws_size,
                              hipStream_t stream) {
    const float* scores = (const float*)d_in[0];
    const int*   labels = (const int*)d_in[1];
    float* ws  = (float*)d_ws;
    float* out = (float*)d_out;

    hipMemsetAsync(ws + ROWSUM_OFF, 0, ZERO_FLOATS * sizeof(float), stream);
    gather_pass<<<QN / 256, 256, 0, stream>>>(scores, labels, ws);
    main_pass<<<NB, TB, 0, stream>>>(scores, ws);
    reduce_pass<<<192, 256, 0, stream>>>(ws);
    final_pass<<<1, 256, 0, stream>>>(ws, out);
}

// Round 3
// 372.171 us; speedup vs baseline: 1.1581x; 1.1581x over previous
//
#include <hip/hip_runtime.h>

// clip_nce: Q=16384 queries, V=4096 videos, scores [Q,V] fp32, labels [Q] int.
// R7 -> R8: REVERT R7's rp[32] deferred reduction (204us @ 1.96 TB/s, VALUBusy
// 4.3% -> registers went to accumulators instead of load buffers). Back to R5's
// proven loop style (unroll 8, in-loop shfl+atomic, lb(256,8), nt loads).
// ONE lever: CONTIGUOUS-PER-BLOCK geometry. Every 6+ TB/s kernel on this chip
// (harness fill 6.7, m13 copy 6.3) streams contiguous-per-block; every ~2.4 TB/s
// sweep variant used 8MB block-strided 1KB islands. Block b now sweeps
// [b*128KB,(b+1)*128KB) = 8 full rows. colacc becomes static c[4][4]
// (q=k&3 compile-time under unroll 8). colcomp grows 8->32MB (+7us reduce).

#define QN 16384
#define VN 4096
#define NB 2048
#define TB 256
#define ITERS 32                          // 8 rows * 4 quarter-rows
#define F4_PER_BLOCK 8192                 // 128 KB contiguous per block

typedef float f32x4 __attribute__((ext_vector_type(4)));

// workspace layout in floats (~33.5 MiB):
#define COLCOMP_OFF 0                     // NB*4096 column partials (full row per block)
#define ROWSUM_OFF  (NB * 4096)           // QN: sum exp per row (global atomics)
#define NOMSUM_OFF  (ROWSUM_OFF + QN)     // VN: sum exp(s) per label
#define COLSUM_OFF  (NOMSUM_OFF + VN)     // VN: column exp-sums (natural order)
#define ACC_OFF     (COLSUM_OFF + VN)     // [0]=sum log rowsum, [1]=sum s
#define ZERO_FLOATS (QN + VN + VN + 8)    // rowsum + nomsum + colsum + acc

// 16384 label gathers (one cache line each) + nomsum + sum(s)
__global__ __launch_bounds__(256) void gather_pass(const float* __restrict__ scores,
                                                   const int* __restrict__ labels,
                                                   float* __restrict__ ws) {
    float* nomsum = ws + NOMSUM_OFF;
    float* acc    = ws + ACC_OFF;
    const int i = blockIdx.x * 256 + threadIdx.x;
    const int lab = labels[i];
    const float s = scores[(size_t)i * VN + lab];
    unsafeAtomicAdd(&nomsum[lab], __expf(s));
    float v = s;
#pragma unroll
    for (int off = 32; off >= 1; off >>= 1)
        v += __shfl_down(v, off);
    if ((threadIdx.x & 63) == 0) unsafeAtomicAdd(&acc[1], v);
}

// Contiguous dense sweep with NON-TEMPORAL reads.
// Block b sweeps f4 indices [b*8192, (b+1)*8192) in 32 steps of 256 f4 (4 KB).
//   iter k: f4 = b*8192 + k*256 + t
//   row = b*8 + (k>>2); col = (k&3)*1024 + t*4 + {0..3}
// In-loop wave reduce + fire-and-forget atomic per iter (R5-proven shape).
__global__ __launch_bounds__(256, 8) void main_pass(const float* __restrict__ scores,
                                                    float* __restrict__ ws) {
    float* rowsum  = ws + ROWSUM_OFF;
    float* colcomp = ws + COLCOMP_OFF;
    const int tid  = threadIdx.x;
    const int b    = blockIdx.x;
    const int lane = tid & 63;
    const f32x4* sp = reinterpret_cast<const f32x4*>(scores);
    const size_t base = (size_t)b * F4_PER_BLOCK + tid;

    float c00=0.f,c01=0.f,c02=0.f,c03=0.f;   // q=0
    float c10=0.f,c11=0.f,c12=0.f,c13=0.f;   // q=1
    float c20=0.f,c21=0.f,c22=0.f,c23=0.f;   // q=2
    float c30=0.f,c31=0.f,c32=0.f,c33=0.f;   // q=3

#pragma unroll 8
    for (int k = 0; k < ITERS; ++k) {
        f32x4 x = __builtin_nontemporal_load(&sp[base + k * 256]);
        float e0 = __expf(x.x), e1 = __expf(x.y);
        float e2 = __expf(x.z), e3 = __expf(x.w);
        // q = k&3 is a compile-time constant inside the unrolled body
        switch (k & 3) {
            case 0: c00 += e0; c01 += e1; c02 += e2; c03 += e3; break;
            case 1: c10 += e0; c11 += e1; c12 += e2; c13 += e3; break;
            case 2: c20 += e0; c21 += e1; c22 += e2; c23 += e3; break;
            case 3: c30 += e0; c31 += e1; c32 += e2; c33 += e3; break;
        }
        float rp = (e0 + e1) + (e2 + e3);
#pragma unroll
        for (int off = 32; off >= 1; off >>= 1)
            rp += __shfl_down(rp, off);
        if (lane == 0)   // 16 atomics per row address total (4 waves x 4 quarter-iters)
            unsafeAtomicAdd(&rowsum[b * 8 + (k >> 2)], rp);
    }

    // col partials: block writes one full 4096-wide row of partials, coalesced.
    // colcomp[b*4096 + q*1024 + t*4 + j] <-> col q*1024 + t*4 + j
    f32x4* cc = reinterpret_cast<f32x4*>(colcomp + (size_t)b * 4096);
    f32x4 o;
    o.x=c00; o.y=c01; o.z=c02; o.w=c03; cc[0 * 256 + tid] = o;
    o.x=c10; o.y=c11; o.z=c12; o.w=c13; cc[1 * 256 + tid] = o;
    o.x=c20; o.y=c21; o.z=c22; o.w=c23; cc[2 * 256 + tid] = o;
    o.x=c30; o.y=c31; o.z=c32; o.w=c33; cc[3 * 256 + tid] = o;
}

// blocks [0,128): colsum from partials (32 MiB read, coalesced).
//   block = mg*16 + cb: b-range mg (8 groups of 256 blocks), col-chunk cb (16 x 256 cols)
// blocks [128,192): sum log rowsum -> acc[0]
__global__ __launch_bounds__(256) void reduce_pass(float* __restrict__ ws) {
    const float* colcomp = ws + COLCOMP_OFF;
    const float* rowsum  = ws + ROWSUM_OFF;
    float* colsum = ws + COLSUM_OFF;
    float* acc    = ws + ACC_OFF;
    const int tid = threadIdx.x;

    if (blockIdx.x < 128) {
        const int mg = blockIdx.x >> 4;          // block-range group 0..7
        const int cb = blockIdx.x & 15;          // 256-col chunk 0..15
        const int c  = cb * 256 + tid;           // column 0..4095
        float sum = 0.0f;
#pragma unroll 4
        for (int m = mg * 256; m < mg * 256 + 256; ++m)
            sum += colcomp[(size_t)m * 4096 + c];
        unsafeAtomicAdd(&colsum[c], sum);
    } else {
        const int idx = (blockIdx.x - 128) * 256 + tid;
        float v = __logf(rowsum[idx]);
#pragma unroll
        for (int off = 32; off >= 1; off >>= 1)
            v += __shfl_down(v, off);
        if ((tid & 63) == 0) unsafeAtomicAdd(&acc[0], v);
    }
}

__global__ __launch_bounds__(256) void final_pass(const float* __restrict__ ws,
                                                  float* __restrict__ out) {
    const float* nomsum = ws + NOMSUM_OFF;
    const float* colsum = ws + COLSUM_OFF;
    const float* acc    = ws + ACC_OFF;
    const int tid = threadIdx.x;

    float local = 0.0f;
    for (int c = tid; c < VN; c += 256)
        local += __logf(colsum[c]) - __logf(nomsum[c]);
#pragma unroll
    for (int off = 32; off >= 1; off >>= 1)
        local += __shfl_down(local, off);
    __shared__ float red[4];
    const int wid = tid >> 6, lane = tid & 63;
    if (lane == 0) red[wid] = local;
    __syncthreads();
    if (tid == 0) {
        const float v2t = (red[0] + red[1]) + (red[2] + red[3]);
        // mean(log rowsum - s) + mean(log colsum - log nomsum)
        out[0] = (acc[0] - acc[1]) * (1.0f / QN) + v2t * (1.0f / VN);
    }
}

extern "C" void kernel_launch(void* const* d_in, const int* in_sizes, int n_in,
                              void* d_out, int out_size, void* d_ws, size_t ws_size,
                              hipStream_t stream) {
    const float* scores = (const float*)d_in[0];
    const int*   labels = (const int*)d_in[1];
    float* ws  = (float*)d_ws;
    float* out = (float*)d_out;

    hipMemsetAsync(ws + ROWSUM_OFF, 0, ZERO_FLOATS * sizeof(float), stream);
    gather_pass<<<QN / 256, 256, 0, stream>>>(scores, labels, ws);
    main_pass<<<NB, TB, 0, stream>>>(scores, ws);
    reduce_pass<<<192, 256, 0, stream>>>(ws);
    final_pass<<<1, 256, 0, stream>>>(ws, out);
}